// Round 1
// baseline (324.836 us; speedup 1.0000x reference)
//
#include <hip/hip_runtime.h>

// Problem constants (from setup_inputs): B=4, D=64, N=2048, T=64, N_obs=1024, K=32
#define BB   4
#define DD   64
#define NN   2048
#define TT   64
#define NOBS 1024
#define KK   32
#define EPSF 1e-8f

// ws layout in floats:
// s     : B*N*D = 524288
// alpha : B*N*K = 262144
// hnum  : B*K*D*T = 524288
// flags : N ints (2048)
// dinv  : B*K (128)
#define S_OFF     0
#define ALPHA_OFF (BB*NN*DD)
#define HNUM_OFF  (ALPHA_OFF + BB*NN*KK)
#define FLAGS_OFF (HNUM_OFF + BB*KK*DD*TT)
#define DINV_OFF  (FLAGS_OFF + NN)

// idx_obs may arrive as int32 or int64 (low word valid; values are arange).
// Detect int64 layout: int32 view would be [0,0,1,0,...] -> idx32[1]==0.
__device__ __forceinline__ int idx_stride(const int* idx) {
  return (idx[1] == 0 && idx[2] == 1) ? 2 : 1;
}

__global__ void k0_mark(const int* __restrict__ idx, int* __restrict__ flags) {
  int i = blockIdx.x * 256 + threadIdx.x;
  int st = idx_stride(idx);
  if (i < NOBS) flags[idx[i * st]] = 1;
}

// K1: masked-mean summary s[b,n,d] for ALL n, fused with out = h copy for observed n.
// grid B*N blocks, 256 threads. Wave w handles 16 d's; 16-lane groups own one row (t as float4).
__global__ __launch_bounds__(256) void k1_summary(
    const float* __restrict__ h, const float* __restrict__ mask,
    const int* __restrict__ flags, float* __restrict__ s,
    float* __restrict__ out) {
  int blk = blockIdx.x;
  int b = blk >> 11;            // / N
  int n = blk & (NN - 1);
  int tid = threadIdx.x;
  int lane = tid & 63;
  int w = tid >> 6;
  int tq = lane & 15;           // float4 slot over T
  int dd = lane >> 4;           // 4 rows per wave-load

  const float4* m4 = reinterpret_cast<const float4*>(mask) + ((size_t)b * NN + n) * (TT / 4);
  float4 mv = m4[tq];
  float msum = mv.x + mv.y + mv.z + mv.w;
  #pragma unroll
  for (int off = 8; off; off >>= 1) msum += __shfl_xor(msum, off);
  msum = fmaxf(msum, 1.0f);
  const bool obs = flags[n] != 0;

  #pragma unroll
  for (int i = 0; i < 4; ++i) {
    int d = (w << 4) + (i << 2) + dd;
    size_t rowf4 = ((((size_t)b * DD + d) * NN + n) * TT) >> 2;
    float4 hv = reinterpret_cast<const float4*>(h)[rowf4 + tq];
    float dot = hv.x * mv.x + hv.y * mv.y + hv.z * mv.z + hv.w * mv.w;
    #pragma unroll
    for (int off = 8; off; off >>= 1) dot += __shfl_xor(dot, off);
    if (tq == 0) s[((size_t)b * NN + n) * DD + d] = dot / msum;
    if (obs) reinterpret_cast<float4*>(out)[rowf4 + tq] = hv;
  }
}

// K2: alpha[b,n,k] = softmax_k( cos(s[b,n,:], proto[k,:]) ). One wave per n, 4 n per block.
__global__ __launch_bounds__(256) void k2_alpha(
    const float* __restrict__ s, const float* __restrict__ proto,
    float* __restrict__ alpha) {
  __shared__ float pT[DD * 33];   // transposed prototypes [d][k], stride 33 (bank-conflict-free)
  __shared__ float pn[KK];
  __shared__ float snL[4][DD];
  int tid = threadIdx.x;
  {
    int k0 = tid >> 6;
    int d = tid & 63;
    #pragma unroll
    for (int i = 0; i < 8; ++i) {
      int k = k0 + (i << 2);
      pT[d * 33 + k] = proto[k * DD + d];
    }
  }
  __syncthreads();
  if (tid < 32) {
    float nsq = 0.f;
    #pragma unroll 8
    for (int d = 0; d < DD; ++d) { float v = pT[d * 33 + tid]; nsq = fmaf(v, v, nsq); }
    pn[tid] = fmaxf(sqrtf(nsq), 1e-12f);
  }
  __syncthreads();
  for (int r = tid; r < DD * KK; r += 256) {
    int d = r >> 5, k = r & 31;
    pT[d * 33 + k] /= pn[k];
  }
  __syncthreads();

  int w = tid >> 6, lane = tid & 63;
  int blk = blockIdx.x;
  int b = blk >> 9;                       // / (N/4)
  int n = ((blk & 511) << 2) + w;

  float sd = s[((size_t)b * NN + n) * DD + lane];
  float nsq = sd * sd;
  #pragma unroll
  for (int off = 32; off; off >>= 1) nsq += __shfl_xor(nsq, off);
  float sn = sd / fmaxf(sqrtf(nsq), 1e-12f);
  snL[w][lane] = sn;
  __syncthreads();

  if (lane < 32) {
    float sim = 0.f;
    #pragma unroll 8
    for (int d = 0; d < DD; ++d) sim = fmaf(snL[w][d], pT[d * 33 + lane], sim);
    float m = sim;
    #pragma unroll
    for (int off = 16; off; off >>= 1) m = fmaxf(m, __shfl_xor(m, off));
    float e = expf(sim - m);
    float sum = e;
    #pragma unroll
    for (int off = 16; off; off >>= 1) sum += __shfl_xor(sum, off);
    alpha[((size_t)b * NN + n) * KK + lane] = e / sum;
  }
}

// K2b: dinv[b,k] = 1 / max(sum_{i in idx} alpha[b,idx[i],k], EPS)
__global__ __launch_bounds__(256) void k2b_dinv(
    const float* __restrict__ alpha, const int* __restrict__ idx,
    float* __restrict__ dinv) {
  __shared__ float red[4];
  int blk = blockIdx.x;             // b*K + k
  int b = blk >> 5, k = blk & 31;
  int tid = threadIdx.x;
  int st = idx_stride(idx);
  float sum = 0.f;
  for (int i = tid; i < NOBS; i += 256) {
    int n = idx[i * st];
    sum += alpha[((size_t)b * NN + n) * KK + k];
  }
  #pragma unroll
  for (int off = 32; off; off >>= 1) sum += __shfl_xor(sum, off);
  if ((tid & 63) == 0) red[tid >> 6] = sum;
  __syncthreads();
  if (tid == 0) {
    float tot = red[0] + red[1] + red[2] + red[3];
    dinv[blk] = 1.0f / fmaxf(tot, EPSF);
  }
}

// K3: hnum[b,k,d,t] += sum_{i in split} alpha[b,idx[i],k] * h[b,d,idx[i],t]  (atomicAdd over 4 splits)
// grid B*D*4 blocks, 256 threads. Wave w owns k in [8w,8w+8); lanes: 16 t-groups x 4 i-subsets.
__global__ __launch_bounds__(256) void k3_hnum(
    const float* __restrict__ h, const float* __restrict__ alpha,
    const int* __restrict__ idx, float* __restrict__ hnum) {
  __shared__ float aL[256 * 33];   // [i][k], stride 33 to avoid 4-way bank conflict on iq-varying reads
  __shared__ int nL[256];
  int blk = blockIdx.x;
  int sp = blk & 3;
  int d = (blk >> 2) & (DD - 1);
  int b = blk >> 8;
  int tid = threadIdx.x;
  int i0 = sp * 256;
  int st = idx_stride(idx);

  for (int r = tid; r < 256 * 32; r += 256) {
    int i = r >> 5, k = r & 31;
    int n = idx[(i0 + i) * st];
    if (k == 0) nL[i] = n;
    aL[i * 33 + k] = alpha[((size_t)b * NN + n) * KK + k];
  }
  __syncthreads();

  int lane = tid & 63, w = tid >> 6;
  int tq = lane & 15, iq = lane >> 4;
  float4 acc[8];
  #pragma unroll
  for (int j = 0; j < 8; ++j) acc[j] = make_float4(0.f, 0.f, 0.f, 0.f);

  const size_t hbase4 = (((size_t)b * DD + d) * NN * TT) >> 2;
  for (int i = 0; i < 256; i += 4) {
    int n = nL[i + iq];
    float4 hv = reinterpret_cast<const float4*>(h)[hbase4 + (size_t)n * (TT / 4) + tq];
    const float* ar = &aL[(i + iq) * 33 + w * 8];
    #pragma unroll
    for (int j = 0; j < 8; ++j) {
      float a = ar[j];
      acc[j].x = fmaf(a, hv.x, acc[j].x);
      acc[j].y = fmaf(a, hv.y, acc[j].y);
      acc[j].z = fmaf(a, hv.z, acc[j].z);
      acc[j].w = fmaf(a, hv.w, acc[j].w);
    }
  }
  // reduce across the 4 iq groups (lane bits 4,5)
  #pragma unroll
  for (int j = 0; j < 8; ++j) {
    acc[j].x += __shfl_xor(acc[j].x, 16); acc[j].x += __shfl_xor(acc[j].x, 32);
    acc[j].y += __shfl_xor(acc[j].y, 16); acc[j].y += __shfl_xor(acc[j].y, 32);
    acc[j].z += __shfl_xor(acc[j].z, 16); acc[j].z += __shfl_xor(acc[j].z, 32);
    acc[j].w += __shfl_xor(acc[j].w, 16); acc[j].w += __shfl_xor(acc[j].w, 32);
  }
  if (iq == 0) {
    #pragma unroll
    for (int j = 0; j < 8; ++j) {
      int k = w * 8 + j;
      size_t o = (((size_t)b * KK + k) * DD + d) * TT + tq * 4;
      atomicAdd(&hnum[o + 0], acc[j].x);
      atomicAdd(&hnum[o + 1], acc[j].y);
      atomicAdd(&hnum[o + 2], acc[j].z);
      atomicAdd(&hnum[o + 3], acc[j].w);
    }
  }
}

// K4: out[b,d,n,t] = sum_k (alpha[b,n,k]*dinv[b,k]) * hnum[b,k,d,t]   for unobserved n.
// grid B*(N/8) blocks; block handles 8 consecutive n, all d,t. hnum served from L2.
__global__ __launch_bounds__(256) void k4_impute(
    const float* __restrict__ hnum, const float* __restrict__ alpha,
    const float* __restrict__ dinv, const int* __restrict__ flags,
    float* __restrict__ out) {
  __shared__ float aL[8][KK];
  __shared__ int fL[8];
  int blk = blockIdx.x;
  int b = blk >> 8;             // / (N/8)
  int n0 = (blk & 255) << 3;
  int tid = threadIdx.x;
  {
    int j = tid >> 5, k = tid & 31;
    aL[j][k] = alpha[((size_t)b * NN + n0 + j) * KK + k] * dinv[b * KK + k];
  }
  if (tid < 8) fL[tid] = flags[n0 + tid];
  __syncthreads();
  if (fL[0] & fL[1] & fL[2] & fL[3] & fL[4] & fL[5] & fL[6] & fL[7]) return;

  int tl = tid & 15;            // t as float4
  int dslot = tid >> 4;
  const float4* hb = reinterpret_cast<const float4*>(hnum);
  #pragma unroll
  for (int it = 0; it < 4; ++it) {
    int d = dslot + (it << 4);
    float4 acc[8];
    #pragma unroll
    for (int j = 0; j < 8; ++j) acc[j] = make_float4(0.f, 0.f, 0.f, 0.f);
    #pragma unroll
    for (int k = 0; k < KK; k += 4) {
      float4 h0 = hb[(((size_t)b * KK + k    ) * DD + d) * (TT / 4) + tl];
      float4 h1 = hb[(((size_t)b * KK + k + 1) * DD + d) * (TT / 4) + tl];
      float4 h2 = hb[(((size_t)b * KK + k + 2) * DD + d) * (TT / 4) + tl];
      float4 h3 = hb[(((size_t)b * KK + k + 3) * DD + d) * (TT / 4) + tl];
      #pragma unroll
      for (int j = 0; j < 8; ++j) {
        float4 av = *reinterpret_cast<const float4*>(&aL[j][k]);
        acc[j].x = fmaf(av.x, h0.x, fmaf(av.y, h1.x, fmaf(av.z, h2.x, fmaf(av.w, h3.x, acc[j].x))));
        acc[j].y = fmaf(av.x, h0.y, fmaf(av.y, h1.y, fmaf(av.z, h2.y, fmaf(av.w, h3.y, acc[j].y))));
        acc[j].z = fmaf(av.x, h0.z, fmaf(av.y, h1.z, fmaf(av.z, h2.z, fmaf(av.w, h3.z, acc[j].z))));
        acc[j].w = fmaf(av.x, h0.w, fmaf(av.y, h1.w, fmaf(av.z, h2.w, fmaf(av.w, h3.w, acc[j].w))));
      }
    }
    #pragma unroll
    for (int j = 0; j < 8; ++j) {
      if (!fL[j]) {
        size_t o4 = ((((size_t)b * DD + d) * NN + (n0 + j)) * TT) >> 2;
        reinterpret_cast<float4*>(out)[o4 + tl] = acc[j];
      }
    }
  }
}

extern "C" void kernel_launch(void* const* d_in, const int* in_sizes, int n_in,
                              void* d_out, int out_size, void* d_ws, size_t ws_size,
                              hipStream_t stream) {
  const float* h     = (const float*)d_in[0];
  const float* mask  = (const float*)d_in[1];
  const int*   idx   = (const int*)d_in[2];
  const float* proto = (const float*)d_in[3];
  float* out = (float*)d_out;
  float* ws  = (float*)d_ws;

  float* s     = ws + S_OFF;
  float* alpha = ws + ALPHA_OFF;
  float* hnum  = ws + HNUM_OFF;
  int*   flags = (int*)(ws + FLAGS_OFF);
  float* dinv  = ws + DINV_OFF;

  // zero hnum (atomic accumulation target) and flags, contiguous region
  hipMemsetAsync(hnum, 0, (size_t)(BB * KK * DD * TT + NN) * sizeof(float), stream);
  k0_mark<<<(NOBS + 255) / 256, 256, 0, stream>>>(idx, flags);
  k1_summary<<<BB * NN, 256, 0, stream>>>(h, mask, flags, s, out);
  k2_alpha<<<BB * (NN / 4), 256, 0, stream>>>(s, proto, alpha);
  k2b_dinv<<<BB * KK, 256, 0, stream>>>(alpha, idx, dinv);
  k3_hnum<<<BB * DD * 4, 256, 0, stream>>>(h, alpha, idx, hnum);
  k4_impute<<<BB * (NN / 8), 256, 0, stream>>>(hnum, alpha, dinv, flags, out);
}